// Round 18
// baseline (104.841 us; speedup 1.0000x reference)
//
#include <hip/hip_runtime.h>
#include <hip/hip_bf16.h>

typedef __attribute__((ext_vector_type(8)))  __bf16 bf16x8;
typedef __attribute__((ext_vector_type(4)))  __bf16 bf16x4;
typedef __attribute__((ext_vector_type(2)))  __bf16 bf16x2;
typedef __attribute__((ext_vector_type(4)))  float  f32x4;

#define MFMA16(a,b,c) __builtin_amdgcn_mfma_f32_16x16x32_bf16((a),(b),(c),0,0,0)

// ---------------------------------------------------------------------------
// Projection GEMM (R15 body): f32 inputs, fused bf16 conversion, BK=32.
// z=0: Q scaled by log2e/sqrt(128), masked rows zeroed -> [bh][s][128].
// z=1: K MFMA16-FRAGMENT-LINEAR: unit = (s>>5)*8 + ((s>>4)&1)*4 + (d>>5);
//      off = (s&15)*8 + ((d&31)>>3)*128 + (d&7).
// z=2: V MFMA16-FRAGMENT-LINEAR: unit = (s>>5)*8 + (d>>4);
//      off = (d&15)*8 + ((s&31)>>3)*128 + (s&7).
// Units are 512 elems -> attn loads are lane-contiguous 1KB wave loads.
// ---------------------------------------------------------------------------
__global__ __launch_bounds__(256, 2) void gemm_kernel(
    const float* __restrict__ Xq, const float* __restrict__ Xk,
    const float* __restrict__ Xv, const float* __restrict__ Wq,
    const float* __restrict__ Wk, const float* __restrict__ Wv,
    const float* __restrict__ bq, const float* __restrict__ bk,
    const float* __restrict__ bv, const int* __restrict__ mask,
    __bf16* __restrict__ dq, __bf16* __restrict__ dk, __bf16* __restrict__ dv)
{
  const int which = blockIdx.z;
  const float* X    = which == 0 ? Xq : which == 1 ? Xk : Xv;
  const float* W    = which == 0 ? Wq : which == 1 ? Wk : Wv;
  const float* bias = which == 0 ? bq : which == 1 ? bk : bv;
  __bf16* dst       = which == 0 ? dq : which == 1 ? dk : dv;
  const float oscale = which == 0 ? 0.12751744710339033f : 1.0f; // log2e/sqrt(128)

  __shared__ __align__(16) __bf16 Al[2][128 * 32];
  __shared__ __align__(16) __bf16 Bl[2][128 * 32];

  const int tid  = threadIdx.x;
  const int lane = tid & 63;
  const int w    = tid >> 6;
  const int wr = w >> 1, wc = w & 1;
  const int mbase = blockIdx.x * 128;
  const int nbase = blockIdx.y * 128;
  const int arow = lane & 15;
  const int hi   = lane >> 4;

  f32x4 acc[4][4] = {};
  float4 ar[4], br[4];

  auto issue = [&](int k0) {
#pragma unroll
    for (int i = 0; i < 4; ++i) {
      int idx = tid + i * 256;
      int r = idx >> 3, c = (idx & 7) * 4;
      ar[i] = *(const float4*)&X[(size_t)(mbase + r) * 512 + k0 + c];
      br[i] = *(const float4*)&W[(size_t)(nbase + r) * 512 + k0 + c];
    }
  };
  auto commit = [&](int buf) {
#pragma unroll
    for (int i = 0; i < 4; ++i) {
      int idx = tid + i * 256;
      int r = idx >> 3, c = (idx & 7) * 4;
      int slot = c >> 3, half = (c >> 2) & 1;
      int addr = r * 32 + (((slot + (r >> 2)) & 3) ^ (r & 3)) * 8 + half * 4;
      bf16x4 av, bv2;
      av[0] = (__bf16)ar[i].x; av[1] = (__bf16)ar[i].y;
      av[2] = (__bf16)ar[i].z; av[3] = (__bf16)ar[i].w;
      bv2[0] = (__bf16)br[i].x; bv2[1] = (__bf16)br[i].y;
      bv2[2] = (__bf16)br[i].z; bv2[3] = (__bf16)br[i].w;
      *(bf16x4*)&Al[buf][addr] = av;
      *(bf16x4*)&Bl[buf][addr] = bv2;
    }
  };

  issue(0);
  commit(0);

  for (int t = 0; t < 16; ++t) {
    const int cur = t & 1;
    if (t < 15) issue((t + 1) * 32);
    __syncthreads();

    __builtin_amdgcn_s_setprio(1);
    {
      bf16x8 af[4], bfr[4];
#pragma unroll
      for (int m = 0; m < 4; ++m) {
        int row = wr * 64 + m * 16 + arow;
        int sl  = (((hi + (row >> 2)) & 3) ^ (row & 3)) * 8;
        af[m] = *(bf16x8*)&Al[cur][row * 32 + sl];
      }
#pragma unroll
      for (int n = 0; n < 4; ++n) {
        int row = wc * 64 + n * 16 + arow;
        int sl  = (((hi + (row >> 2)) & 3) ^ (row & 3)) * 8;
        bfr[n] = *(bf16x8*)&Bl[cur][row * 32 + sl];
      }
#pragma unroll
      for (int m = 0; m < 4; ++m)
#pragma unroll
        for (int n = 0; n < 4; ++n)
          acc[m][n] = MFMA16(af[m], bfr[n], acc[m][n]);
    }
    __builtin_amdgcn_s_setprio(0);

    if (t < 15) commit(cur ^ 1);
  }

#pragma unroll
  for (int n = 0; n < 4; ++n) {
    int col = nbase + wc * 64 + n * 16 + arow;
    float bsv = bias[col];
    int hd = col >> 7, d = col & 127;
#pragma unroll
    for (int m = 0; m < 4; ++m) {
      int row0 = mbase + wr * 64 + m * 16 + hi * 4;
#pragma unroll
      for (int r = 0; r < 4; ++r) {
        float v = acc[m][n][r] + bsv;
        v = (v > 0.0f ? v : 0.0f) * oscale;
        int mm = row0 + r;
        int b = mm >> 11, s = mm & 2047;
        if (which == 0 && mask[b * 2048 + s] != 0) v = 0.0f;
        size_t bhoff = (size_t)(b * 4 + hd) * (2048 * 128);
        if (which == 0) {
          dst[bhoff + (size_t)s * 128 + d] = (__bf16)v;
        } else if (which == 1) {
          size_t unit = (size_t)(s >> 5) * 8 + ((s >> 4) & 1) * 4 + (d >> 5);
          dst[bhoff + unit * 512 + (s & 15) * 8 + ((d & 31) >> 3) * 128 +
              (d & 7)] = (__bf16)v;
        } else {
          size_t unit = (size_t)(s >> 5) * 8 + (d >> 4);
          dst[bhoff + unit * 512 + (d & 15) * 8 + ((s & 31) >> 3) * 128 +
              (s & 7)] = (__bf16)v;
        }
      }
    }
  }
}

// ---------------------------------------------------------------------------
// Flash attention, MFMA16 low-footprint redesign: 16 q-rows/wave -> oacc 32
// regs (was 64), total ~145 unified -> 3 waves/SIMD with 4096 waves of work.
// Barrier-free main loop, K/V stream direct from fragment-linear global,
// loadK(i+1) after QK(i), loadV(i+1) after PV(i) (compiler auto-vmcnt gives
// each a full phase of latency cover). P exchange: cvt_pk + 8 shfl + selects.
// grid 1024 = 8 XCD x (2 bh x 64 qt); block 256 = 2 q-sub x 2 kv-halves.
// ---------------------------------------------------------------------------
__global__ __launch_bounds__(256) void attn_kernel(
    const __bf16* __restrict__ qh, const __bf16* __restrict__ kfr,
    const __bf16* __restrict__ vfr, const float* __restrict__ queries,
    float* __restrict__ out)
{
  __shared__ float Ml[2][16];
  __shared__ __align__(16) float Ob[2 * 8 * 256];   // [qw][dt][lane*4]

  const int tid  = threadIdx.x;
  const int lane = tid & 63;
  const int w    = tid >> 6;
  const int qw   = w & 1;          // q-subtile
  const int kw   = w >> 1;         // kv-half
  const int q16  = lane & 15;
  const int hi4  = lane >> 4;      // 0..3

  const int blk  = blockIdx.x;     // 0..1023
  const int xcd  = blk & 7;
  const int rest = blk >> 3;       // 0..127
  const int bh   = xcd * 2 + (rest & 1);
  const int qt   = rest >> 1;      // 0..63
  const int b = bh >> 2, hd = bh & 3;
  const int qbase = qt * 32 + qw * 16;

  const __bf16* qptr = qh  + (size_t)bh * 2048 * 128;
  const __bf16* kp   = kfr + (size_t)bh * 2048 * 128;
  const __bf16* vp   = vfr + (size_t)bh * 2048 * 128;

  // Q B-frags: B[k=d][n=q]: n = lane&15, k-slice elems at (lane>>4)*8.
  bf16x8 qf[4];
#pragma unroll
  for (int sl = 0; sl < 4; ++sl)
    qf[sl] = *(const bf16x8*)
        &qptr[(size_t)(qbase + q16) * 128 + sl * 32 + hi4 * 8];

  // Shuffle sources for P exchange (constant per lane).
  const int srcA = q16 + (((2 * hi4) & 3) << 4);
  const int srcB = q16 + (((2 * hi4 + 1) & 3) << 4);
  const bool selhi = hi4 >= 2;

  float l_st = 0.f;
  f32x4 oacc[8] = {};
  bf16x8 kf[2][4], vf[8];

  // wave kw owns 32-kv chunks c = i*2 + kw, i = 0..31.
  auto loadK = [&](int i) {
    size_t cb = (size_t)(i * 2 + kw) * 8 * 512;
#pragma unroll
    for (int hh = 0; hh < 2; ++hh)
#pragma unroll
      for (int sl = 0; sl < 4; ++sl)
        kf[hh][sl] = *(const bf16x8*)
            &kp[cb + (size_t)(hh * 4 + sl) * 512 + lane * 8];
  };
  auto loadV = [&](int i) {
    size_t cb = (size_t)(i * 2 + kw) * 8 * 512;
#pragma unroll
    for (int dt = 0; dt < 8; ++dt)
      vf[dt] = *(const bf16x8*)&vp[cb + (size_t)dt * 512 + lane * 8];
  };

  loadK(0);
  loadV(0);

  for (int i = 0; i < 32; ++i) {
    // QK^T: two independent 4-deep MFMA16 chains. S[kv][q]: col=lane&15=q,
    // row=(lane>>4)*4+reg = kv (within 16-half).
    f32x4 s0 = {}, s1 = {};
    __builtin_amdgcn_s_setprio(1);
#pragma unroll
    for (int sl = 0; sl < 4; ++sl) s0 = MFMA16(kf[0][sl], qf[sl], s0);
#pragma unroll
    for (int sl = 0; sl < 4; ++sl) s1 = MFMA16(kf[1][sl], qf[sl], s1);
    __builtin_amdgcn_s_setprio(0);

    if (i + 1 < 32) loadK(i + 1);   // kf free after QK issue; covered by SM+PV

    // Fixed-reference softmax (log2 domain, Q pre-scaled; masked rows Q==0).
    float p0[4], p1[4];
#pragma unroll
    for (int r = 0; r < 4; ++r) {
      p0[r] = __builtin_amdgcn_exp2f(s0[r]);
      p1[r] = __builtin_amdgcn_exp2f(s1[r]);
    }
    l_st += ((p0[0] + p0[1]) + (p0[2] + p0[3])) +
            ((p1[0] + p1[1]) + (p1[2] + p1[3]));

    // P -> B-frag: pack pairs, then gather kv=8g..8g+7 via 8 shfl + selects.
    unsigned pk0[2], pk1[2];
    {
      bf16x2 t0, t1, t2, t3;
      t0[0] = (__bf16)p0[0]; t0[1] = (__bf16)p0[1];
      t1[0] = (__bf16)p0[2]; t1[1] = (__bf16)p0[3];
      t2[0] = (__bf16)p1[0]; t2[1] = (__bf16)p1[1];
      t3[0] = (__bf16)p1[2]; t3[1] = (__bf16)p1[3];
      pk0[0] = __builtin_bit_cast(unsigned, t0);
      pk0[1] = __builtin_bit_cast(unsigned, t1);
      pk1[0] = __builtin_bit_cast(unsigned, t2);
      pk1[1] = __builtin_bit_cast(unsigned, t3);
    }
    unsigned w0a = __shfl(pk0[0], srcA), w0b = __shfl(pk1[0], srcA);
    unsigned w1a = __shfl(pk0[1], srcA), w1b = __shfl(pk1[1], srcA);
    unsigned w2a = __shfl(pk0[0], srcB), w2b = __shfl(pk1[0], srcB);
    unsigned w3a = __shfl(pk0[1], srcB), w3b = __shfl(pk1[1], srcB);
    union { unsigned u[4]; bf16x8 v; } pu;
    pu.u[0] = selhi ? w0b : w0a;
    pu.u[1] = selhi ? w1b : w1a;
    pu.u[2] = selhi ? w2b : w2a;
    pu.u[3] = selhi ? w3b : w3a;
    bf16x8 pf = pu.v;

    // PV: 8 independent MFMA16 (one per 16-d tile).
    __builtin_amdgcn_s_setprio(1);
#pragma unroll
    for (int dt = 0; dt < 8; ++dt)
      oacc[dt] = MFMA16(vf[dt], pf, oacc[dt]);
    __builtin_amdgcn_s_setprio(0);

    if (i + 1 < 32) loadV(i + 1);   // vf free after PV issue; covered by QK(i+1)
  }

  // l reduce over hi-groups (rows spread across lane>>4).
  l_st += __shfl_xor(l_st, 16);
  l_st += __shfl_xor(l_st, 32);

  // ---- merge kv-halves (plain sums), then scramble epilogue ----
  __syncthreads();
  if (kw == 1) {
    if (lane < 16) Ml[qw][lane] = l_st;
#pragma unroll
    for (int dt = 0; dt < 8; ++dt)
      *(f32x4*)&Ob[(qw * 8 + dt) * 256 + lane * 4] = oacc[dt];
  }
  __syncthreads();

  if (kw == 0) {
    float inv = 1.0f / (l_st + Ml[qw][q16]);
    const int qg = qbase + q16;
    const int qhi = qg >> 9;
    const int col = qg & 511;
#pragma unroll
    for (int dt = 0; dt < 8; ++dt) {
      f32x4 o1 = *(const f32x4*)&Ob[(qw * 8 + dt) * 256 + lane * 4];
#pragma unroll
      for (int r = 0; r < 4; ++r) {
        int d = dt * 16 + hi4 * 4 + r;
        int srow = hd * 512 + d * 4 + qhi;
        size_t o = ((size_t)b * 2048 + srow) * 512 + col;
        out[o] = (oacc[dt][r] + o1[r]) * inv + queries[o];
      }
    }
  }
}

extern "C" void kernel_launch(void* const* d_in, const int* in_sizes, int n_in,
                              void* d_out, int out_size, void* d_ws, size_t ws_size,
                              hipStream_t stream) {
  const float* queries = (const float*)d_in[0];
  const float* keys    = (const float*)d_in[1];
  const float* values  = (const float*)d_in[2];
  const int*   mask    = (const int*)d_in[3];
  const float* Wq = (const float*)d_in[4];
  const float* bq = (const float*)d_in[5];
  const float* Wk = (const float*)d_in[6];
  const float* bk = (const float*)d_in[7];
  const float* Wv = (const float*)d_in[8];
  const float* bv = (const float*)d_in[9];
  float* out = (float*)d_out;

  const size_t perX = (size_t)8192 * 512;
  __bf16* qhp = (__bf16*)d_ws;
  __bf16* khp = qhp + perX;
  __bf16* vtp = khp + perX;

  gemm_kernel<<<dim3(64, 4, 3), dim3(256), 0, stream>>>(
      queries, keys, values, Wq, Wk, Wv, bq, bk, bv, mask, qhp, khp, vtp);

  attn_kernel<<<dim3(1024), dim3(256), 0, stream>>>(qhp, khp, vtp, queries, out);
}